// Round 1
// 1021.184 us; speedup vs baseline: 1.1620x; 1.1620x over previous
//
#include <hip/hip_runtime.h>
#include <type_traits>

#define BDIM 8
#define LDIM 2048
#define DDIM 1024
#define NL 3
#define K4 4
#define MDIM (BDIM * LDIM) /* 16384 rows */
#define BK 64
#define NT (DDIM / BK) /* 16 K-tiles */

typedef __bf16 bf16x8 __attribute__((ext_vector_type(8)));
typedef __bf16 bf16x4 __attribute__((ext_vector_type(4)));
typedef float f32x4 __attribute__((ext_vector_type(4)));
typedef const __attribute__((address_space(1))) void gvoid_t;
typedef __attribute__((address_space(3))) void svoid_t;

// wave-uniform LDS base; lane l's 16B lands at base + l*16 (m104/m108).
__device__ __forceinline__ void load16(const void* g, void* lds_uniform) {
    __builtin_amdgcn_global_load_lds((gvoid_t*)g, (svoid_t*)lds_uniform, 16, 0, 0);
}

// raw barrier (no vmcnt drain) with compiler memory fences on both sides
#define SBAR()                                  \
    do {                                        \
        asm volatile("" ::: "memory");          \
        __builtin_amdgcn_s_barrier();           \
        asm volatile("" ::: "memory");          \
    } while (0)
#define WAITV(N) asm volatile("s_waitcnt vmcnt(" #N ")" ::: "memory")

__global__ void cvt_bf16(const float* __restrict__ s, __bf16* __restrict__ d, int n) {
    int i = blockIdx.x * 256 + threadIdx.x;
    if (i < n) d[i] = (__bf16)s[i];
}

// interleave Wr/Wi rows: W2[l][2d][k] = Wr[l][d][k], W2[l][2d+1][k] = Wi[l][d][k]
__global__ __launch_bounds__(256) void cvt_interleave(const float* __restrict__ wr,
                                                      const float* __restrict__ wi,
                                                      __bf16* __restrict__ w2, int n) {
    int i = blockIdx.x * 256 + threadIdx.x;
    if (i >= n) return;
    int k = i & (DDIM - 1);
    int ld = i >> 10; /* l*D + d */
    int l = ld >> 10;
    int d = ld & (DDIM - 1);
    size_t base = ((size_t)l * 2 * DDIM + 2 * d) * DDIM + k;
    w2[base] = (__bf16)wr[i];
    w2[base + DDIM] = (__bf16)wi[i];
}

// causal depthwise conv1d k=4, left pad 3. X:(B,L,D) -> XC:(B,L,D) bf16
template <typename T>
__global__ __launch_bounds__(256) void conv_kernel(const T* __restrict__ X,
                                                   const float* __restrict__ cw,
                                                   const float* __restrict__ cb,
                                                   __bf16* __restrict__ XC) {
    int idx = blockIdx.x * 256 + threadIdx.x;
    int d = (idx & (DDIM / 4 - 1)) << 2;
    int t = (idx >> 8) & (LDIM - 1);
    int b = idx >> 19;
    float wv[4][4];
    *(float4*)wv[0] = ((const float4*)cw)[d + 0];
    *(float4*)wv[1] = ((const float4*)cw)[d + 1];
    *(float4*)wv[2] = ((const float4*)cw)[d + 2];
    *(float4*)wv[3] = ((const float4*)cw)[d + 3];
    float4 cbv = *(const float4*)(cb + d);
    float acc[4] = {cbv.x, cbv.y, cbv.z, cbv.w};
#pragma unroll
    for (int k = 0; k < K4; k++) {
        int tt = t + k - (K4 - 1);
        if (tt >= 0) {
            size_t off = ((size_t)(b * LDIM + tt) << 10) + d;
            float xv[4];
            if constexpr (std::is_same<T, float>::value) {
                float4 v = *(const float4*)(X + off);
                xv[0] = v.x; xv[1] = v.y; xv[2] = v.z; xv[3] = v.w;
            } else {
                bf16x4 v = *(const bf16x4*)(X + off);
                xv[0] = (float)v.x; xv[1] = (float)v.y; xv[2] = (float)v.z; xv[3] = (float)v.w;
            }
#pragma unroll
            for (int j = 0; j < 4; j++) acc[j] += xv[j] * wv[j][k];
        }
    }
    bf16x4 o;
    o.x = (__bf16)acc[0]; o.y = (__bf16)acc[1]; o.z = (__bf16)acc[2]; o.w = (__bf16)acc[3];
    *(bf16x4*)(XC + ((size_t)(b * LDIM + t) << 10) + d) = o;
}

// ---- 256x256-tile 8-phase GEMM (T1+T2+T3+T4+T5), BK=64, 8 waves ----
// C[m][n] = sum_k A[m][k] * W2[n][k]; N merged = 2048 (cols alternate r,i).
// Gate epilogue: LDS transpose -> coalesced sigmoid/exp gate math.
__global__ __launch_bounds__(512, 2) void gate_gemm(
    const __bf16* __restrict__ A, const __bf16* __restrict__ W2,
    const float* __restrict__ wrb, const float* __restrict__ wib,
    const float* __restrict__ la,
    __bf16* __restrict__ LOGA, __bf16* __restrict__ BB) {
    __shared__ __attribute__((aligned(16))) __bf16 sm[4][16384]; // 128 KiB: [buf*2+mat][256*64]
    int tid = threadIdx.x;
    int wave = tid >> 6, lane = tid & 63;
    int wm = wave >> 2, wn = wave & 3; // 2M x 4N waves, each 128x64 out
    int fr = lane & 15, quad = lane >> 4;

    // T1: bijective XCD swizzle (nwg % 8 == 0)
    int nx = gridDim.x;
    int bid = blockIdx.y * nx + blockIdx.x;
    int cpx = (nx * gridDim.y) >> 3;
    int sw = (bid & 7) * cpx + (bid >> 3);
    int bm0 = (sw / nx) * 256;
    int bn0 = (sw % nx) * 256; // merged-N origin

    const __bf16* Ag = A + (size_t)bm0 * DDIM;
    const __bf16* Bg = W2 + (size_t)bn0 * DDIM;

    f32x4 acc[8][4];
    f32x4 zero = {0.f, 0.f, 0.f, 0.f};
#pragma unroll
    for (int i = 0; i < 8; i++)
#pragma unroll
        for (int j = 0; j < 4; j++) acc[i][j] = zero;

    // stage one full K-tile (A+B, 2 halves each) = 8 load16/thread; XOR-swizzled source
    auto STAGE = [&](int buf, int ko) {
#pragma unroll
        for (int h = 0; h < 2; h++)
#pragma unroll
            for (int j = 0; j < 2; j++) {
                int ci = j * 512 + tid; // chunk id in half-tile [128 rows][8 chunks]
                int r = ci >> 3;
                int g = (ci & 7) ^ (r & 7); // pre-swizzled global chunk
                size_t go = (size_t)(h * 128 + r) * DDIM + ko + g * 8;
                int lb = h * 8192 + j * 4096 + wave * 512; // wave-uniform element base
                load16(Ag + go, &sm[buf * 2][lb]);
                load16(Bg + go, &sm[buf * 2 + 1][lb]);
            }
    };

    STAGE(0, 0);
    int c = 0;
    for (int t = 0; t < NT; t++) {
        SBAR(); // all waves done reading buf[c^1] (prev tile) before overwrite
        if (t + 1 < NT) {
            STAGE(c ^ 1, (t + 1) * BK);
            WAITV(8); // counted: tile t's 8 loads done, t+1's 8 stay in flight
        } else {
            WAITV(0);
        }
        SBAR();
        const __bf16* Ac = sm[c * 2];
        const __bf16* Bc = sm[c * 2 + 1];
#pragma unroll
        for (int ph = 0; ph < 4; ph++) {
            if (ph) SBAR();
            const int mh = ph & 1, kw = ph >> 1;
            bf16x8 af[4], bfm[4];
#pragma unroll
            for (int mi = 0; mi < 4; mi++) {
                int row = wm * 128 + (mh * 4 + mi) * 16 + fr;
                af[mi] = *(const bf16x8*)(Ac + row * 64 + ((kw * 4 + quad) ^ (row & 7)) * 8);
            }
#pragma unroll
            for (int ni = 0; ni < 4; ni++) {
                int row = wn * 64 + ni * 16 + fr;
                bfm[ni] = *(const bf16x8*)(Bc + row * 64 + ((kw * 4 + quad) ^ (row & 7)) * 8);
            }
            __builtin_amdgcn_s_setprio(1);
#pragma unroll
            for (int ni = 0; ni < 4; ni++)
#pragma unroll
                for (int mi = 0; mi < 4; mi++)
                    acc[mh * 4 + mi][ni] = __builtin_amdgcn_mfma_f32_16x16x32_bf16(
                        af[mi], bfm[ni], acc[mh * 4 + mi][ni], 0, 0, 0);
            __builtin_amdgcn_s_setprio(0);
        }
        c ^= 1;
    }

    // ---- gate epilogue: per mi, dump 32x256 f32 slice, re-read transposed ----
    float* Lt = (float*)&sm[0][0]; // [32][260] f32 (stride 260: quad rows 2-way only)
    int colg = (tid & 31) * 8;     // 8 merged cols = 4 (r,i) pairs
    int d0 = (bn0 >> 1) + (colg >> 1);
    float rb[4], ibv[4], lnab[4];
    {
        float4 r4 = *(const float4*)(wrb + d0);
        float4 i4 = *(const float4*)(wib + d0);
        float4 l4 = *(const float4*)(la + d0);
        float lav[4] = {l4.x, l4.y, l4.z, l4.w};
        rb[0] = r4.x; rb[1] = r4.y; rb[2] = r4.z; rb[3] = r4.w;
        ibv[0] = i4.x; ibv[1] = i4.y; ibv[2] = i4.z; ibv[3] = i4.w;
#pragma unroll
        for (int j = 0; j < 4; j++) lnab[j] = __logf(1.f / (1.f + __expf(-lav[j])));
    }
#pragma unroll
    for (int mi = 0; mi < 8; mi++) {
        __syncthreads();
#pragma unroll
        for (int ni = 0; ni < 4; ni++) {
            int col = wn * 64 + ni * 16 + fr;
#pragma unroll
            for (int reg = 0; reg < 4; reg++)
                Lt[(wm * 16 + quad * 4 + reg) * 260 + col] = acc[mi][ni][reg];
        }
        __syncthreads();
#pragma unroll
        for (int hf = 0; hf < 2; hf++) {
            int r = (tid >> 5) + hf * 16;
            int m = bm0 + (r >> 4) * 128 + mi * 16 + (r & 15);
            float vv[8];
            *(f32x4*)&vv[0] = *(const f32x4*)&Lt[r * 260 + colg];
            *(f32x4*)&vv[4] = *(const f32x4*)&Lt[r * 260 + colg + 4];
            bf16x4 xcv = *(const bf16x4*)(A + (size_t)m * DDIM + d0);
            bf16x4 og, ob;
#pragma unroll
            for (int j = 0; j < 4; j++) {
                float rv = 1.f / (1.f + __expf(-(vv[2 * j] + rb[j])));
                float iv = 1.f / (1.f + __expf(-(vv[2 * j + 1] + ibv[j])));
                float lga = 8.f * rv * lnab[j];
                float a = __expf(lga);
                float bt = sqrtf(fmaxf(1.f - a * a, 1e-6f)) * (iv * (float)xcv[j]);
                og[j] = (__bf16)lga;
                ob[j] = (__bf16)bt;
            }
            *(bf16x4*)(LOGA + (size_t)m * DDIM + d0) = og;
            *(bf16x4*)(BB + (size_t)m * DDIM + d0) = ob;
        }
    }
}

// HW = A @ Wo^T, same 8-phase structure, plain transposed epilogue.
__global__ __launch_bounds__(512, 2) void out_gemm(
    const __bf16* __restrict__ A, const __bf16* __restrict__ Wo, __bf16* __restrict__ HW) {
    __shared__ __attribute__((aligned(16))) __bf16 sm[4][16384];
    int tid = threadIdx.x;
    int wave = tid >> 6, lane = tid & 63;
    int wm = wave >> 2, wn = wave & 3;
    int fr = lane & 15, quad = lane >> 4;

    int nx = gridDim.x;
    int bid = blockIdx.y * nx + blockIdx.x;
    int cpx = (nx * gridDim.y) >> 3;
    int sw = (bid & 7) * cpx + (bid >> 3);
    int bm0 = (sw / nx) * 256;
    int bn0 = (sw % nx) * 256;

    const __bf16* Ag = A + (size_t)bm0 * DDIM;
    const __bf16* Bg = Wo + (size_t)bn0 * DDIM;

    f32x4 acc[8][4];
    f32x4 zero = {0.f, 0.f, 0.f, 0.f};
#pragma unroll
    for (int i = 0; i < 8; i++)
#pragma unroll
        for (int j = 0; j < 4; j++) acc[i][j] = zero;

    auto STAGE = [&](int buf, int ko) {
#pragma unroll
        for (int h = 0; h < 2; h++)
#pragma unroll
            for (int j = 0; j < 2; j++) {
                int ci = j * 512 + tid;
                int r = ci >> 3;
                int g = (ci & 7) ^ (r & 7);
                size_t go = (size_t)(h * 128 + r) * DDIM + ko + g * 8;
                int lb = h * 8192 + j * 4096 + wave * 512;
                load16(Ag + go, &sm[buf * 2][lb]);
                load16(Bg + go, &sm[buf * 2 + 1][lb]);
            }
    };

    STAGE(0, 0);
    int c = 0;
    for (int t = 0; t < NT; t++) {
        SBAR();
        if (t + 1 < NT) {
            STAGE(c ^ 1, (t + 1) * BK);
            WAITV(8);
        } else {
            WAITV(0);
        }
        SBAR();
        const __bf16* Ac = sm[c * 2];
        const __bf16* Bc = sm[c * 2 + 1];
#pragma unroll
        for (int ph = 0; ph < 4; ph++) {
            if (ph) SBAR();
            const int mh = ph & 1, kw = ph >> 1;
            bf16x8 af[4], bfm[4];
#pragma unroll
            for (int mi = 0; mi < 4; mi++) {
                int row = wm * 128 + (mh * 4 + mi) * 16 + fr;
                af[mi] = *(const bf16x8*)(Ac + row * 64 + ((kw * 4 + quad) ^ (row & 7)) * 8);
            }
#pragma unroll
            for (int ni = 0; ni < 4; ni++) {
                int row = wn * 64 + ni * 16 + fr;
                bfm[ni] = *(const bf16x8*)(Bc + row * 64 + ((kw * 4 + quad) ^ (row & 7)) * 8);
            }
            __builtin_amdgcn_s_setprio(1);
#pragma unroll
            for (int ni = 0; ni < 4; ni++)
#pragma unroll
                for (int mi = 0; mi < 4; mi++)
                    acc[mh * 4 + mi][ni] = __builtin_amdgcn_mfma_f32_16x16x32_bf16(
                        af[mi], bfm[ni], acc[mh * 4 + mi][ni], 0, 0, 0);
            __builtin_amdgcn_s_setprio(0);
        }
        c ^= 1;
    }

    float* Lt = (float*)&sm[0][0]; // [32][260]
    int colg = (tid & 31) * 8;
    int n0 = bn0 + colg;
#pragma unroll
    for (int mi = 0; mi < 8; mi++) {
        __syncthreads();
#pragma unroll
        for (int ni = 0; ni < 4; ni++) {
            int col = wn * 64 + ni * 16 + fr;
#pragma unroll
            for (int reg = 0; reg < 4; reg++)
                Lt[(wm * 16 + quad * 4 + reg) * 260 + col] = acc[mi][ni][reg];
        }
        __syncthreads();
#pragma unroll
        for (int hf = 0; hf < 2; hf++) {
            int r = (tid >> 5) + hf * 16;
            int m = bm0 + (r >> 4) * 128 + mi * 16 + (r & 15);
            float vv[8];
            *(f32x4*)&vv[0] = *(const f32x4*)&Lt[r * 260 + colg];
            *(f32x4*)&vv[4] = *(const f32x4*)&Lt[r * 260 + colg + 4];
            bf16x8 o;
#pragma unroll
            for (int j = 0; j < 8; j++) o[j] = (__bf16)vv[j];
            *(bf16x8*)(HW + (size_t)m * DDIM + n0) = o;
        }
    }
}

// Clamped log-space scan (reference-equivalent telescoped recurrence), bf16 IO, fp32 math.
#define SC_T (LDIM / 8) /* 256 */
__global__ __launch_bounds__(256) void scan_kernel(const __bf16* __restrict__ LOGA,
                                                   const __bf16* __restrict__ BB,
                                                   __bf16* __restrict__ H) {
    int b = blockIdx.y;
    int dl = threadIdx.x & 31;
    int d = blockIdx.x * 32 + dl;
    int c = threadIdx.x >> 5;
    size_t base = ((size_t)b * LDIM + (size_t)c * SC_T) * DDIM + d;
    const __bf16* pga = LOGA + base;
    const __bf16* pbb = BB + base;
    __bf16* pH = H + base;

    float S = 0.f;
#pragma unroll 8
    for (int t = 0; t < SC_T; t++) S += (float)pga[(size_t)t * DDIM];
    __shared__ float sS[8][32];
    sS[c][dl] = S;
    __syncthreads();
    float L0 = 0.f;
    for (int cc = 0; cc < c; cc++) L0 += sS[cc][dl];

    float Lr = L0, lcp = fmaxf(L0, -80.f), hB = 0.f;
#pragma unroll 4
    for (int t = 0; t < SC_T; t++) {
        float lga = (float)pga[(size_t)t * DDIM];
        Lr += lga;
        float lc = fmaxf(Lr, -80.f);
        hB = __expf(lc - lcp) * hB + (float)pbb[(size_t)t * DDIM];
        lcp = lc;
    }
    float Ac = __expf(fmaxf(Lr, -80.f) - fmaxf(L0, -80.f));
    __shared__ float sA[8][32], sB[8][32];
    sA[c][dl] = Ac;
    sB[c][dl] = hB;
    __syncthreads();
    float hin = 0.f;
    for (int cc = 0; cc < c; cc++) hin = sA[cc][dl] * hin + sB[cc][dl];

    Lr = L0;
    lcp = fmaxf(L0, -80.f);
    float h = hin;
#pragma unroll 4
    for (int t = 0; t < SC_T; t++) {
        float lga = (float)pga[(size_t)t * DDIM];
        Lr += lga;
        float lc = fmaxf(Lr, -80.f);
        h = __expf(lc - lcp) * h + (float)pbb[(size_t)t * DDIM];
        lcp = lc;
        pH[(size_t)t * DDIM] = (__bf16)h;
    }
}

// rmsnorm over last dim (1024); one block per row, 256 threads x 4 elems.
template <typename TI, typename TO>
__global__ __launch_bounds__(256) void rmsnorm_kernel(const TI* __restrict__ X,
                                                      const float* __restrict__ w,
                                                      TO* __restrict__ Y) {
    int row = blockIdx.x;
    int tid = threadIdx.x;
    size_t off = (size_t)row * DDIM + tid * 4;
    float v[4];
    if constexpr (std::is_same<TI, float>::value) {
        float4 t = *(const float4*)(X + off);
        v[0] = t.x; v[1] = t.y; v[2] = t.z; v[3] = t.w;
    } else {
        bf16x4 t = *(const bf16x4*)(X + off);
        v[0] = (float)t.x; v[1] = (float)t.y; v[2] = (float)t.z; v[3] = (float)t.w;
    }
    float s = v[0] * v[0] + v[1] * v[1] + v[2] * v[2] + v[3] * v[3];
#pragma unroll
    for (int o = 32; o > 0; o >>= 1) s += __shfl_down(s, o);
    __shared__ float sw[4];
    if ((tid & 63) == 0) sw[tid >> 6] = s;
    __syncthreads();
    float tot = sw[0] + sw[1] + sw[2] + sw[3];
    float scale = rsqrtf(tot * (1.f / (float)DDIM) + 1e-6f);
    float4 wv = ((const float4*)w)[tid];
    float o0 = v[0] * wv.x * scale, o1 = v[1] * wv.y * scale;
    float o2 = v[2] * wv.z * scale, o3 = v[3] * wv.w * scale;
    if constexpr (std::is_same<TO, float>::value) {
        float4 o = {o0, o1, o2, o3};
        *(float4*)(Y + off) = o;
    } else {
        bf16x4 o;
        o.x = (__bf16)o0; o.y = (__bf16)o1; o.z = (__bf16)o2; o.w = (__bf16)o3;
        *(bf16x4*)(Y + off) = o;
    }
}

extern "C" void kernel_launch(void* const* d_in, const int* in_sizes, int n_in,
                              void* d_out, int out_size, void* d_ws, size_t ws_size,
                              hipStream_t stream) {
    const float* x = (const float*)d_in[0];
    const float* conv_w = (const float*)d_in[1];
    const float* conv_b = (const float*)d_in[2];
    const float* wr_w = (const float*)d_in[3];
    const float* wr_b = (const float*)d_in[4];
    const float* wi_w = (const float*)d_in[5];
    const float* wi_b = (const float*)d_in[6];
    const float* log_a = (const float*)d_in[7];
    const float* wo_w = (const float*)d_in[8];
    const float* norm_w = (const float*)d_in[9];
    const float* norm_out_w = (const float*)d_in[10];

    const size_t W2SZ = (size_t)NL * 2 * DDIM * DDIM; /* interleaved r/i weight */
    const size_t WOSZ = (size_t)NL * DDIM * DDIM;
    const size_t MD = (size_t)MDIM * DDIM;
    __bf16* w2 = (__bf16*)d_ws;
    __bf16* wo16 = w2 + W2SZ;
    __bf16* XC = wo16 + WOSZ;
    __bf16* LGA = XC + MD;
    __bf16* BBf = LGA + MD;
    __bf16* Hb = BBf + MD;
    __bf16* HWb = Hb + MD;
    __bf16* PNb = HWb + MD;

    int nw = (int)WOSZ;
    cvt_interleave<<<(nw + 255) / 256, 256, 0, stream>>>(wr_w, wi_w, w2, nw);
    cvt_bf16<<<(nw + 255) / 256, 256, 0, stream>>>(wo_w, wo16, nw);

    for (int l = 0; l < NL; l++) {
        if (l == 0)
            conv_kernel<float><<<(MDIM * (DDIM / 4)) / 256, 256, 0, stream>>>(
                x, conv_w, conv_b, XC);
        else
            conv_kernel<__bf16><<<(MDIM * (DDIM / 4)) / 256, 256, 0, stream>>>(
                PNb, conv_w + (size_t)l * DDIM * K4, conv_b + (size_t)l * DDIM, XC);
        gate_gemm<<<dim3(2 * DDIM / 256, MDIM / 256), 512, 0, stream>>>(
            XC, w2 + (size_t)l * 2 * DDIM * DDIM,
            wr_b + (size_t)l * DDIM, wi_b + (size_t)l * DDIM, log_a + (size_t)l * DDIM,
            LGA, BBf);
        scan_kernel<<<dim3(DDIM / 32, BDIM), 256, 0, stream>>>(LGA, BBf, Hb);
        out_gemm<<<dim3(DDIM / 256, MDIM / 256), 512, 0, stream>>>(
            Hb, wo16 + (size_t)l * DDIM * DDIM, HWb);
        rmsnorm_kernel<__bf16, __bf16><<<MDIM, 256, 0, stream>>>(
            HWb, norm_w + (size_t)l * DDIM, PNb);
    }
    rmsnorm_kernel<__bf16, float><<<MDIM, 256, 0, stream>>>(PNb, norm_out_w, (float*)d_out);
}

// Round 2
// 1004.264 us; speedup vs baseline: 1.1815x; 1.0168x over previous
//
#include <hip/hip_runtime.h>
#include <type_traits>

#define BDIM 8
#define LDIM 2048
#define DDIM 1024
#define NL 3
#define K4 4
#define MDIM (BDIM * LDIM) /* 16384 rows */
#define BK32 32
#define NT32 (DDIM / BK32) /* 32 K-tiles */

typedef __bf16 bf16x8 __attribute__((ext_vector_type(8)));
typedef __bf16 bf16x4 __attribute__((ext_vector_type(4)));
typedef float f32x4 __attribute__((ext_vector_type(4)));
typedef const __attribute__((address_space(1))) void gvoid_t;
typedef __attribute__((address_space(3))) void svoid_t;

// wave-uniform LDS base; lane l's 16B lands at base + l*16 (m104/m108).
__device__ __forceinline__ void load16(const void* g, void* lds_uniform) {
    __builtin_amdgcn_global_load_lds((gvoid_t*)g, (svoid_t*)lds_uniform, 16, 0, 0);
}

// raw barrier (no vmcnt drain) with compiler memory fences on both sides
#define SBAR()                                  \
    do {                                        \
        asm volatile("" ::: "memory");          \
        __builtin_amdgcn_s_barrier();           \
        asm volatile("" ::: "memory");          \
    } while (0)
#define WAITV(N) asm volatile("s_waitcnt vmcnt(" #N ")" ::: "memory")

__global__ void cvt_bf16(const float* __restrict__ s, __bf16* __restrict__ d, int n) {
    int i = blockIdx.x * 256 + threadIdx.x;
    if (i < n) d[i] = (__bf16)s[i];
}

// interleave Wr/Wi rows: W2[l][2d][k] = Wr[l][d][k], W2[l][2d+1][k] = Wi[l][d][k]
__global__ __launch_bounds__(256) void cvt_interleave(const float* __restrict__ wr,
                                                      const float* __restrict__ wi,
                                                      __bf16* __restrict__ w2, int n) {
    int i = blockIdx.x * 256 + threadIdx.x;
    if (i >= n) return;
    int k = i & (DDIM - 1);
    int ld = i >> 10; /* l*D + d */
    int l = ld >> 10;
    int d = ld & (DDIM - 1);
    size_t base = ((size_t)l * 2 * DDIM + 2 * d) * DDIM + k;
    w2[base] = (__bf16)wr[i];
    w2[base + DDIM] = (__bf16)wi[i];
}

// causal depthwise conv1d k=4, left pad 3. X:(B,L,D) -> XC:(B,L,D) bf16
template <typename T>
__global__ __launch_bounds__(256) void conv_kernel(const T* __restrict__ X,
                                                   const float* __restrict__ cw,
                                                   const float* __restrict__ cb,
                                                   __bf16* __restrict__ XC) {
    int idx = blockIdx.x * 256 + threadIdx.x;
    int d = (idx & (DDIM / 4 - 1)) << 2;
    int t = (idx >> 8) & (LDIM - 1);
    int b = idx >> 19;
    float wv[4][4];
    *(float4*)wv[0] = ((const float4*)cw)[d + 0];
    *(float4*)wv[1] = ((const float4*)cw)[d + 1];
    *(float4*)wv[2] = ((const float4*)cw)[d + 2];
    *(float4*)wv[3] = ((const float4*)cw)[d + 3];
    float4 cbv = *(const float4*)(cb + d);
    float acc[4] = {cbv.x, cbv.y, cbv.z, cbv.w};
#pragma unroll
    for (int k = 0; k < K4; k++) {
        int tt = t + k - (K4 - 1);
        if (tt >= 0) {
            size_t off = ((size_t)(b * LDIM + tt) << 10) + d;
            float xv[4];
            if constexpr (std::is_same<T, float>::value) {
                float4 v = *(const float4*)(X + off);
                xv[0] = v.x; xv[1] = v.y; xv[2] = v.z; xv[3] = v.w;
            } else {
                bf16x4 v = *(const bf16x4*)(X + off);
                xv[0] = (float)v.x; xv[1] = (float)v.y; xv[2] = (float)v.z; xv[3] = (float)v.w;
            }
#pragma unroll
            for (int j = 0; j < 4; j++) acc[j] += xv[j] * wv[j][k];
        }
    }
    bf16x4 o;
    o.x = (__bf16)acc[0]; o.y = (__bf16)acc[1]; o.z = (__bf16)acc[2]; o.w = (__bf16)acc[3];
    *(bf16x4*)(XC + ((size_t)(b * LDIM + t) << 10) + d) = o;
}

// ---- 256x256-tile deep-pipelined GEMM: BK=32, 4 LDS buffers, depth-3 prefetch ----
// one WAITV(8)+barrier per K-tile; no inter-phase barriers; B-frags read once/tile.
// swizzle: LDS[r][sc] holds global chunk sc ^ ((r>>1)&3)  (chunk = 8 bf16 = 16B).
__global__ __launch_bounds__(512, 2) void gate_gemm(
    const __bf16* __restrict__ A, const __bf16* __restrict__ W2,
    const float* __restrict__ wrb, const float* __restrict__ wib,
    const float* __restrict__ la,
    __bf16* __restrict__ LOGA, __bf16* __restrict__ BB) {
    __shared__ __attribute__((aligned(16))) __bf16 sm[4][2][8192]; // 128 KiB
    int tid = threadIdx.x;
    int wave = tid >> 6, lane = tid & 63;
    int wm = wave >> 2, wn = wave & 3; // 2M x 4N waves, each 128x64 out
    int fr = lane & 15, quad = lane >> 4;

    int nx = gridDim.x;
    int bid = blockIdx.y * nx + blockIdx.x;
    int cpx = (nx * gridDim.y) >> 3;
    int sw = (bid & 7) * cpx + (bid >> 3);
    int bm0 = (sw / nx) * 256;
    int bn0 = (sw % nx) * 256; // merged-N origin

    const __bf16* Ag = A + (size_t)bm0 * DDIM;
    const __bf16* Bg = W2 + (size_t)bn0 * DDIM;

    f32x4 acc[8][4];
    f32x4 zero = {0.f, 0.f, 0.f, 0.f};
#pragma unroll
    for (int i = 0; i < 8; i++)
#pragma unroll
        for (int j = 0; j < 4; j++) acc[i][j] = zero;

    // stage one K-tile (A+B, 16KB each) = 4 load16/wave, pre-swizzled global src
    auto STAGE = [&](int buf, int ko) {
#pragma unroll
        for (int j = 0; j < 2; j++) {
            int ci = j * 512 + tid; // chunk id: 256 rows x 4 chunks
            int r = ci >> 2;
            int g = (ci & 3) ^ ((r >> 1) & 3);
            size_t go = (size_t)r * DDIM + ko + g * 8;
            int lb = j * 4096 + wave * 512; // wave-uniform element base
            load16(Ag + go, &sm[buf][0][lb]);
            load16(Bg + go, &sm[buf][1][lb]);
        }
    };

    STAGE(0, 0);
    STAGE(1, BK32);
    STAGE(2, 2 * BK32);
    for (int t4 = 0; t4 < NT32; t4 += 4) {
#pragma unroll
        for (int tt = 0; tt < 4; tt++) {
            int t = t4 + tt;
            // counted wait: 12 in flight -> oldest tile's 4 done; tail drains
            if (t + 2 < NT32) { WAITV(8); }
            else if (t + 1 < NT32) { WAITV(4); }
            else { WAITV(0); }
            SBAR(); // all waves: tile-t loads landed; buf[(t+3)&3] free to overwrite
            if (t + 3 < NT32) STAGE((tt + 3) & 3, (t + 3) * BK32);
            const __bf16* Ac = &sm[tt][0][0];
            const __bf16* Bc = &sm[tt][1][0];
            bf16x8 bfm[4];
#pragma unroll
            for (int ni = 0; ni < 4; ni++) {
                int row = wn * 64 + ni * 16 + fr;
                bfm[ni] = *(const bf16x8*)(Bc + row * 32 + ((quad ^ ((row >> 1) & 3)) << 3));
            }
#pragma unroll
            for (int mh = 0; mh < 2; mh++) {
                bf16x8 af[4];
#pragma unroll
                for (int mi = 0; mi < 4; mi++) {
                    int row = wm * 128 + (mh * 4 + mi) * 16 + fr;
                    af[mi] = *(const bf16x8*)(Ac + row * 32 + ((quad ^ ((row >> 1) & 3)) << 3));
                }
                __builtin_amdgcn_s_setprio(1);
#pragma unroll
                for (int ni = 0; ni < 4; ni++)
#pragma unroll
                    for (int mi = 0; mi < 4; mi++)
                        acc[mh * 4 + mi][ni] = __builtin_amdgcn_mfma_f32_16x16x32_bf16(
                            af[mi], bfm[ni], acc[mh * 4 + mi][ni], 0, 0, 0);
                __builtin_amdgcn_s_setprio(0);
            }
        }
    }

    // ---- gate epilogue: per mi, dump 32x256 f32 slice, re-read transposed ----
    float* Lt = (float*)&sm[0][0][0]; // [32][260] f32 = 33 KB
    int colg = (tid & 31) * 8;        // 8 merged cols = 4 (r,i) pairs
    int d0 = (bn0 >> 1) + (colg >> 1);
    float rb[4], ibv[4], lnab[4];
    {
        float4 r4 = *(const float4*)(wrb + d0);
        float4 i4 = *(const float4*)(wib + d0);
        float4 l4 = *(const float4*)(la + d0);
        float lav[4] = {l4.x, l4.y, l4.z, l4.w};
        rb[0] = r4.x; rb[1] = r4.y; rb[2] = r4.z; rb[3] = r4.w;
        ibv[0] = i4.x; ibv[1] = i4.y; ibv[2] = i4.z; ibv[3] = i4.w;
#pragma unroll
        for (int j = 0; j < 4; j++) lnab[j] = __logf(1.f / (1.f + __expf(-lav[j])));
    }
#pragma unroll
    for (int mi = 0; mi < 8; mi++) {
        __syncthreads();
#pragma unroll
        for (int ni = 0; ni < 4; ni++) {
            int col = wn * 64 + ni * 16 + fr;
#pragma unroll
            for (int reg = 0; reg < 4; reg++)
                Lt[(wm * 16 + quad * 4 + reg) * 260 + col] = acc[mi][ni][reg];
        }
        __syncthreads();
#pragma unroll
        for (int hf = 0; hf < 2; hf++) {
            int r = (tid >> 5) + hf * 16;
            int m = bm0 + (r >> 4) * 128 + mi * 16 + (r & 15);
            float vv[8];
            *(f32x4*)&vv[0] = *(const f32x4*)&Lt[r * 260 + colg];
            *(f32x4*)&vv[4] = *(const f32x4*)&Lt[r * 260 + colg + 4];
            bf16x4 xcv = *(const bf16x4*)(A + (size_t)m * DDIM + d0);
            bf16x4 og, ob;
#pragma unroll
            for (int j = 0; j < 4; j++) {
                float rv = 1.f / (1.f + __expf(-(vv[2 * j] + rb[j])));
                float iv = 1.f / (1.f + __expf(-(vv[2 * j + 1] + ibv[j])));
                float lga = 8.f * rv * lnab[j];
                float a = __expf(lga);
                float bt = sqrtf(fmaxf(1.f - a * a, 1e-6f)) * (iv * (float)xcv[j]);
                og[j] = (__bf16)lga;
                ob[j] = (__bf16)bt;
            }
            *(bf16x4*)(LOGA + (size_t)m * DDIM + d0) = og;
            *(bf16x4*)(BB + (size_t)m * DDIM + d0) = ob;
        }
    }
}

// HW = A @ Wo^T, same deep-pipelined structure, plain transposed epilogue.
__global__ __launch_bounds__(512, 2) void out_gemm(
    const __bf16* __restrict__ A, const __bf16* __restrict__ Wo, __bf16* __restrict__ HW) {
    __shared__ __attribute__((aligned(16))) __bf16 sm[4][2][8192]; // 128 KiB
    int tid = threadIdx.x;
    int wave = tid >> 6, lane = tid & 63;
    int wm = wave >> 2, wn = wave & 3;
    int fr = lane & 15, quad = lane >> 4;

    int nx = gridDim.x;
    int bid = blockIdx.y * nx + blockIdx.x;
    int cpx = (nx * gridDim.y) >> 3;
    int sw = (bid & 7) * cpx + (bid >> 3);
    int bm0 = (sw / nx) * 256;
    int bn0 = (sw % nx) * 256;

    const __bf16* Ag = A + (size_t)bm0 * DDIM;
    const __bf16* Bg = Wo + (size_t)bn0 * DDIM;

    f32x4 acc[8][4];
    f32x4 zero = {0.f, 0.f, 0.f, 0.f};
#pragma unroll
    for (int i = 0; i < 8; i++)
#pragma unroll
        for (int j = 0; j < 4; j++) acc[i][j] = zero;

    auto STAGE = [&](int buf, int ko) {
#pragma unroll
        for (int j = 0; j < 2; j++) {
            int ci = j * 512 + tid;
            int r = ci >> 2;
            int g = (ci & 3) ^ ((r >> 1) & 3);
            size_t go = (size_t)r * DDIM + ko + g * 8;
            int lb = j * 4096 + wave * 512;
            load16(Ag + go, &sm[buf][0][lb]);
            load16(Bg + go, &sm[buf][1][lb]);
        }
    };

    STAGE(0, 0);
    STAGE(1, BK32);
    STAGE(2, 2 * BK32);
    for (int t4 = 0; t4 < NT32; t4 += 4) {
#pragma unroll
        for (int tt = 0; tt < 4; tt++) {
            int t = t4 + tt;
            if (t + 2 < NT32) { WAITV(8); }
            else if (t + 1 < NT32) { WAITV(4); }
            else { WAITV(0); }
            SBAR();
            if (t + 3 < NT32) STAGE((tt + 3) & 3, (t + 3) * BK32);
            const __bf16* Ac = &sm[tt][0][0];
            const __bf16* Bc = &sm[tt][1][0];
            bf16x8 bfm[4];
#pragma unroll
            for (int ni = 0; ni < 4; ni++) {
                int row = wn * 64 + ni * 16 + fr;
                bfm[ni] = *(const bf16x8*)(Bc + row * 32 + ((quad ^ ((row >> 1) & 3)) << 3));
            }
#pragma unroll
            for (int mh = 0; mh < 2; mh++) {
                bf16x8 af[4];
#pragma unroll
                for (int mi = 0; mi < 4; mi++) {
                    int row = wm * 128 + (mh * 4 + mi) * 16 + fr;
                    af[mi] = *(const bf16x8*)(Ac + row * 32 + ((quad ^ ((row >> 1) & 3)) << 3));
                }
                __builtin_amdgcn_s_setprio(1);
#pragma unroll
                for (int ni = 0; ni < 4; ni++)
#pragma unroll
                    for (int mi = 0; mi < 4; mi++)
                        acc[mh * 4 + mi][ni] = __builtin_amdgcn_mfma_f32_16x16x32_bf16(
                            af[mi], bfm[ni], acc[mh * 4 + mi][ni], 0, 0, 0);
                __builtin_amdgcn_s_setprio(0);
            }
        }
    }

    float* Lt = (float*)&sm[0][0][0]; // [32][260]
    int colg = (tid & 31) * 8;
    int n0 = bn0 + colg;
#pragma unroll
    for (int mi = 0; mi < 8; mi++) {
        __syncthreads();
#pragma unroll
        for (int ni = 0; ni < 4; ni++) {
            int col = wn * 64 + ni * 16 + fr;
#pragma unroll
            for (int reg = 0; reg < 4; reg++)
                Lt[(wm * 16 + quad * 4 + reg) * 260 + col] = acc[mi][ni][reg];
        }
        __syncthreads();
#pragma unroll
        for (int hf = 0; hf < 2; hf++) {
            int r = (tid >> 5) + hf * 16;
            int m = bm0 + (r >> 4) * 128 + mi * 16 + (r & 15);
            float vv[8];
            *(f32x4*)&vv[0] = *(const f32x4*)&Lt[r * 260 + colg];
            *(f32x4*)&vv[4] = *(const f32x4*)&Lt[r * 260 + colg + 4];
            bf16x8 o;
#pragma unroll
            for (int j = 0; j < 8; j++) o[j] = (__bf16)vv[j];
            *(bf16x8*)(HW + (size_t)m * DDIM + n0) = o;
        }
    }
}

// Clamped log-space scan (reference-equivalent telescoped recurrence), bf16 IO, fp32 math.
#define SC_T (LDIM / 8) /* 256 */
__global__ __launch_bounds__(256) void scan_kernel(const __bf16* __restrict__ LOGA,
                                                   const __bf16* __restrict__ BB,
                                                   __bf16* __restrict__ H) {
    int b = blockIdx.y;
    int dl = threadIdx.x & 31;
    int d = blockIdx.x * 32 + dl;
    int c = threadIdx.x >> 5;
    size_t base = ((size_t)b * LDIM + (size_t)c * SC_T) * DDIM + d;
    const __bf16* pga = LOGA + base;
    const __bf16* pbb = BB + base;
    __bf16* pH = H + base;

    float S = 0.f;
#pragma unroll 8
    for (int t = 0; t < SC_T; t++) S += (float)pga[(size_t)t * DDIM];
    __shared__ float sS[8][32];
    sS[c][dl] = S;
    __syncthreads();
    float L0 = 0.f;
    for (int cc = 0; cc < c; cc++) L0 += sS[cc][dl];

    float Lr = L0, lcp = fmaxf(L0, -80.f), hB = 0.f;
#pragma unroll 4
    for (int t = 0; t < SC_T; t++) {
        float lga = (float)pga[(size_t)t * DDIM];
        Lr += lga;
        float lc = fmaxf(Lr, -80.f);
        hB = __expf(lc - lcp) * hB + (float)pbb[(size_t)t * DDIM];
        lcp = lc;
    }
    float Ac = __expf(fmaxf(Lr, -80.f) - fmaxf(L0, -80.f));
    __shared__ float sA[8][32], sB[8][32];
    sA[c][dl] = Ac;
    sB[c][dl] = hB;
    __syncthreads();
    float hin = 0.f;
    for (int cc = 0; cc < c; cc++) hin = sA[cc][dl] * hin + sB[cc][dl];

    Lr = L0;
    lcp = fmaxf(L0, -80.f);
    float h = hin;
#pragma unroll 4
    for (int t = 0; t < SC_T; t++) {
        float lga = (float)pga[(size_t)t * DDIM];
        Lr += lga;
        float lc = fmaxf(Lr, -80.f);
        h = __expf(lc - lcp) * h + (float)pbb[(size_t)t * DDIM];
        lcp = lc;
        pH[(size_t)t * DDIM] = (__bf16)h;
    }
}

// rmsnorm over last dim (1024); one block per row, 256 threads x 4 elems.
template <typename TI, typename TO>
__global__ __launch_bounds__(256) void rmsnorm_kernel(const TI* __restrict__ X,
                                                      const float* __restrict__ w,
                                                      TO* __restrict__ Y) {
    int row = blockIdx.x;
    int tid = threadIdx.x;
    size_t off = (size_t)row * DDIM + tid * 4;
    float v[4];
    if constexpr (std::is_same<TI, float>::value) {
        float4 t = *(const float4*)(X + off);
        v[0] = t.x; v[1] = t.y; v[2] = t.z; v[3] = t.w;
    } else {
        bf16x4 t = *(const bf16x4*)(X + off);
        v[0] = (float)t.x; v[1] = (float)t.y; v[2] = (float)t.z; v[3] = (float)t.w;
    }
    float s = v[0] * v[0] + v[1] * v[1] + v[2] * v[2] + v[3] * v[3];
#pragma unroll
    for (int o = 32; o > 0; o >>= 1) s += __shfl_down(s, o);
    __shared__ float sw[4];
    if ((tid & 63) == 0) sw[tid >> 6] = s;
    __syncthreads();
    float tot = sw[0] + sw[1] + sw[2] + sw[3];
    float scale = rsqrtf(tot * (1.f / (float)DDIM) + 1e-6f);
    float4 wv = ((const float4*)w)[tid];
    float o0 = v[0] * wv.x * scale, o1 = v[1] * wv.y * scale;
    float o2 = v[2] * wv.z * scale, o3 = v[3] * wv.w * scale;
    if constexpr (std::is_same<TO, float>::value) {
        float4 o = {o0, o1, o2, o3};
        *(float4*)(Y + off) = o;
    } else {
        bf16x4 o;
        o.x = (__bf16)o0; o.y = (__bf16)o1; o.z = (__bf16)o2; o.w = (__bf16)o3;
        *(bf16x4*)(Y + off) = o;
    }
}

extern "C" void kernel_launch(void* const* d_in, const int* in_sizes, int n_in,
                              void* d_out, int out_size, void* d_ws, size_t ws_size,
                              hipStream_t stream) {
    const float* x = (const float*)d_in[0];
    const float* conv_w = (const float*)d_in[1];
    const float* conv_b = (const float*)d_in[2];
    const float* wr_w = (const float*)d_in[3];
    const float* wr_b = (const float*)d_in[4];
    const float* wi_w = (const float*)d_in[5];
    const float* wi_b = (const float*)d_in[6];
    const float* log_a = (const float*)d_in[7];
    const float* wo_w = (const float*)d_in[8];
    const float* norm_w = (const float*)d_in[9];
    const float* norm_out_w = (const float*)d_in[10];

    const size_t W2SZ = (size_t)NL * 2 * DDIM * DDIM; /* interleaved r/i weight */
    const size_t WOSZ = (size_t)NL * DDIM * DDIM;
    const size_t MD = (size_t)MDIM * DDIM;
    __bf16* w2 = (__bf16*)d_ws;
    __bf16* wo16 = w2 + W2SZ;
    __bf16* XC = wo16 + WOSZ;
    __bf16* LGA = XC + MD;
    __bf16* BBf = LGA + MD;
    __bf16* Hb = BBf + MD;
    __bf16* HWb = Hb + MD;
    __bf16* PNb = HWb + MD;

    int nw = (int)WOSZ;
    cvt_interleave<<<(nw + 255) / 256, 256, 0, stream>>>(wr_w, wi_w, w2, nw);
    cvt_bf16<<<(nw + 255) / 256, 256, 0, stream>>>(wo_w, wo16, nw);

    for (int l = 0; l < NL; l++) {
        if (l == 0)
            conv_kernel<float><<<(MDIM * (DDIM / 4)) / 256, 256, 0, stream>>>(
                x, conv_w, conv_b, XC);
        else
            conv_kernel<__bf16><<<(MDIM * (DDIM / 4)) / 256, 256, 0, stream>>>(
                PNb, conv_w + (size_t)l * DDIM * K4, conv_b + (size_t)l * DDIM, XC);
        gate_gemm<<<dim3(2 * DDIM / 256, MDIM / 256), 512, 0, stream>>>(
            XC, w2 + (size_t)l * 2 * DDIM * DDIM,
            wr_b + (size_t)l * DDIM, wi_b + (size_t)l * DDIM, log_a + (size_t)l * DDIM,
            LGA, BBf);
        scan_kernel<<<dim3(DDIM / 32, BDIM), 256, 0, stream>>>(LGA, BBf, Hb);
        out_gemm<<<dim3(DDIM / 256, MDIM / 256), 512, 0, stream>>>(
            Hb, wo16 + (size_t)l * DDIM * DDIM, HWb);
        rmsnorm_kernel<__bf16, __bf16><<<MDIM, 256, 0, stream>>>(
            HWb, norm_w + (size_t)l * DDIM, PNb);
    }
    rmsnorm_kernel<__bf16, float><<<MDIM, 256, 0, stream>>>(PNb, norm_out_w, (float*)d_out);
}

// Round 3
// 911.445 us; speedup vs baseline: 1.3019x; 1.1018x over previous
//
#include <hip/hip_runtime.h>
#include <type_traits>

#define BDIM 8
#define LDIM 2048
#define DDIM 1024
#define NL 3
#define K4 4
#define MDIM (BDIM * LDIM) /* 16384 rows */
#define BK32 32
#define NT32 (DDIM / BK32) /* 32 K-tiles */

typedef __bf16 bf16x8 __attribute__((ext_vector_type(8)));
typedef __bf16 bf16x4 __attribute__((ext_vector_type(4)));
typedef float f32x4 __attribute__((ext_vector_type(4)));
typedef const __attribute__((address_space(1))) void gvoid_t;
typedef __attribute__((address_space(3))) void svoid_t;

// wave-uniform LDS base; lane l's 16B lands at base + l*16 (m104/m108).
__device__ __forceinline__ void load16(const void* g, void* lds_uniform) {
    __builtin_amdgcn_global_load_lds((gvoid_t*)g, (svoid_t*)lds_uniform, 16, 0, 0);
}

// raw barrier (no vmcnt drain) with compiler memory fences on both sides
#define SBAR()                                  \
    do {                                        \
        asm volatile("" ::: "memory");          \
        __builtin_amdgcn_s_barrier();           \
        asm volatile("" ::: "memory");          \
    } while (0)
#define WAITV(N) asm volatile("s_waitcnt vmcnt(" #N ")" ::: "memory")

__global__ void cvt_bf16(const float* __restrict__ s, __bf16* __restrict__ d, int n) {
    int i = blockIdx.x * 256 + threadIdx.x;
    if (i < n) d[i] = (__bf16)s[i];
}

// interleave Wr/Wi rows: W2[l][2d][k] = Wr[l][d][k], W2[l][2d+1][k] = Wi[l][d][k]
__global__ __launch_bounds__(256) void cvt_interleave(const float* __restrict__ wr,
                                                      const float* __restrict__ wi,
                                                      __bf16* __restrict__ w2, int n) {
    int i = blockIdx.x * 256 + threadIdx.x;
    if (i >= n) return;
    int k = i & (DDIM - 1);
    int ld = i >> 10; /* l*D + d */
    int l = ld >> 10;
    int d = ld & (DDIM - 1);
    size_t base = ((size_t)l * 2 * DDIM + 2 * d) * DDIM + k;
    w2[base] = (__bf16)wr[i];
    w2[base + DDIM] = (__bf16)wi[i];
}

// causal depthwise conv1d k=4, left pad 3. X:(B,L,D) -> XC:(B,L,D) bf16
template <typename T>
__global__ __launch_bounds__(256) void conv_kernel(const T* __restrict__ X,
                                                   const float* __restrict__ cw,
                                                   const float* __restrict__ cb,
                                                   __bf16* __restrict__ XC) {
    int idx = blockIdx.x * 256 + threadIdx.x;
    int d = (idx & (DDIM / 4 - 1)) << 2;
    int t = (idx >> 8) & (LDIM - 1);
    int b = idx >> 19;
    float wv[4][4];
    *(float4*)wv[0] = ((const float4*)cw)[d + 0];
    *(float4*)wv[1] = ((const float4*)cw)[d + 1];
    *(float4*)wv[2] = ((const float4*)cw)[d + 2];
    *(float4*)wv[3] = ((const float4*)cw)[d + 3];
    float4 cbv = *(const float4*)(cb + d);
    float acc[4] = {cbv.x, cbv.y, cbv.z, cbv.w};
#pragma unroll
    for (int k = 0; k < K4; k++) {
        int tt = t + k - (K4 - 1);
        if (tt >= 0) {
            size_t off = ((size_t)(b * LDIM + tt) << 10) + d;
            float xv[4];
            if constexpr (std::is_same<T, float>::value) {
                float4 v = *(const float4*)(X + off);
                xv[0] = v.x; xv[1] = v.y; xv[2] = v.z; xv[3] = v.w;
            } else {
                bf16x4 v = *(const bf16x4*)(X + off);
                xv[0] = (float)v.x; xv[1] = (float)v.y; xv[2] = (float)v.z; xv[3] = (float)v.w;
            }
#pragma unroll
            for (int j = 0; j < 4; j++) acc[j] += xv[j] * wv[j][k];
        }
    }
    bf16x4 o;
    o.x = (__bf16)acc[0]; o.y = (__bf16)acc[1]; o.z = (__bf16)acc[2]; o.w = (__bf16)acc[3];
    *(bf16x4*)(XC + ((size_t)(b * LDIM + t) << 10) + d) = o;
}

// ---- 256x256-tile deep-pipelined GEMM: BK=32, 4 LDS buffers, depth-3 prefetch ----
// hoisted addressing: 12 frag offsets + 4 staging ptrs precomputed; stage offsets fold
// to 13-bit immediates; ds reads are base(tt)+off (1 v_add each).
__global__ __launch_bounds__(512, 2) void gate_gemm(
    const __bf16* __restrict__ A, const __bf16* __restrict__ W2,
    const float* __restrict__ wrb, const float* __restrict__ wib,
    const float* __restrict__ la,
    __bf16* __restrict__ LOGA, __bf16* __restrict__ BB) {
    __shared__ __attribute__((aligned(16))) __bf16 sm[65536]; // 128 KiB: [buf4][mat2][8192]
    int tid = threadIdx.x;
    int wave = tid >> 6, lane = tid & 63;
    int wm = wave >> 2, wn = wave & 3; // 2M x 4N waves, each 128x64 out
    int fr = lane & 15, quad = lane >> 4;

    int nx = gridDim.x;
    int bid = blockIdx.y * nx + blockIdx.x;
    int cpx = (nx * gridDim.y) >> 3;
    int sw = (bid & 7) * cpx + (bid >> 3);
    int bm0 = (sw / nx) * 256;
    int bn0 = (sw % nx) * 256; // merged-N origin

    const __bf16* Ag = A + (size_t)bm0 * DDIM;
    const __bf16* Bg = W2 + (size_t)bn0 * DDIM;

    f32x4 acc[8][4];
    f32x4 zero = {0.f, 0.f, 0.f, 0.f};
#pragma unroll
    for (int i = 0; i < 8; i++)
#pragma unroll
        for (int j = 0; j < 4; j++) acc[i][j] = zero;

    // hoisted fragment LDS offsets (elements, within buffer 0)
    int offA[2][4], offB[4];
#pragma unroll
    for (int mh = 0; mh < 2; mh++)
#pragma unroll
        for (int mi = 0; mi < 4; mi++) {
            int row = wm * 128 + (mh * 4 + mi) * 16 + fr;
            offA[mh][mi] = row * 32 + ((quad ^ ((row >> 1) & 3)) << 3);
        }
#pragma unroll
    for (int ni = 0; ni < 4; ni++) {
        int row = wn * 64 + ni * 16 + fr;
        offB[ni] = 8192 + row * 32 + ((quad ^ ((row >> 1) & 3)) << 3);
    }
    // hoisted staging addresses (pre-swizzled global src, wave-uniform LDS dest)
    int r0 = tid >> 2, g0 = (tid & 3) ^ ((r0 >> 1) & 3);
    int r1 = (512 + tid) >> 2, g1 = ((512 + tid) & 3) ^ ((r1 >> 1) & 3);
    const __bf16* gA0 = Ag + (size_t)r0 * DDIM + g0 * 8;
    const __bf16* gA1 = Ag + (size_t)r1 * DDIM + g1 * 8;
    const __bf16* gB0 = Bg + (size_t)r0 * DDIM + g0 * 8;
    const __bf16* gB1 = Bg + (size_t)r1 * DDIM + g1 * 8;
    int lb0 = wave * 512, lb1 = 4096 + wave * 512;

    auto STAGE = [&](int buf, const __bf16* pA0, const __bf16* pA1,
                     const __bf16* pB0, const __bf16* pB1, int tc) {
        int lo = buf * 16384;
        load16(pA0 + tc * BK32, sm + lo + lb0);
        load16(pA1 + tc * BK32, sm + lo + lb1);
        load16(pB0 + tc * BK32, sm + lo + 8192 + lb0);
        load16(pB1 + tc * BK32, sm + lo + 8192 + lb1);
    };

    STAGE(0, gA0, gA1, gB0, gB1, 0);
    STAGE(1, gA0, gA1, gB0, gB1, 1);
    STAGE(2, gA0, gA1, gB0, gB1, 2);
    for (int t4 = 0; t4 < NT32; t4 += 4) {
        // per-t4 hoisted staging base: stage targets tiles t4+3+tt
        const __bf16* pA0 = gA0 + (t4 + 3) * BK32;
        const __bf16* pA1 = gA1 + (t4 + 3) * BK32;
        const __bf16* pB0 = gB0 + (t4 + 3) * BK32;
        const __bf16* pB1 = gB1 + (t4 + 3) * BK32;
#pragma unroll
        for (int tt = 0; tt < 4; tt++) {
            int t = t4 + tt;
            if (t + 2 < NT32) { WAITV(8); }
            else if (t + 1 < NT32) { WAITV(4); }
            else { WAITV(0); }
            SBAR(); // tile-t loads landed; buf[(t+3)&3] free to overwrite
            if (t + 3 < NT32) STAGE((tt + 3) & 3, pA0, pA1, pB0, pB1, tt);
            const __bf16* base = sm + tt * 16384;
            bf16x8 bfm[4];
#pragma unroll
            for (int ni = 0; ni < 4; ni++) bfm[ni] = *(const bf16x8*)(base + offB[ni]);
#pragma unroll
            for (int mh = 0; mh < 2; mh++) {
                bf16x8 af[4];
#pragma unroll
                for (int mi = 0; mi < 4; mi++)
                    af[mi] = *(const bf16x8*)(base + offA[mh][mi]);
                __builtin_amdgcn_s_setprio(1);
#pragma unroll
                for (int ni = 0; ni < 4; ni++)
#pragma unroll
                    for (int mi = 0; mi < 4; mi++)
                        acc[mh * 4 + mi][ni] = __builtin_amdgcn_mfma_f32_16x16x32_bf16(
                            af[mi], bfm[ni], acc[mh * 4 + mi][ni], 0, 0, 0);
                __builtin_amdgcn_s_setprio(0);
            }
        }
    }

    // ---- gate epilogue: per mi, dump 32x256 f32 slice, re-read transposed ----
    float* Lt = (float*)&sm[0]; // [32][260] f32 = 33 KB
    int colg = (tid & 31) * 8;  // 8 merged cols = 4 (r,i) pairs
    int d0 = (bn0 >> 1) + (colg >> 1);
    float rb[4], ibv[4], lnab[4];
    {
        float4 r4 = *(const float4*)(wrb + d0);
        float4 i4 = *(const float4*)(wib + d0);
        float4 l4 = *(const float4*)(la + d0);
        float lav[4] = {l4.x, l4.y, l4.z, l4.w};
        rb[0] = r4.x; rb[1] = r4.y; rb[2] = r4.z; rb[3] = r4.w;
        ibv[0] = i4.x; ibv[1] = i4.y; ibv[2] = i4.z; ibv[3] = i4.w;
#pragma unroll
        for (int j = 0; j < 4; j++) lnab[j] = __logf(1.f / (1.f + __expf(-lav[j])));
    }
#pragma unroll
    for (int mi = 0; mi < 8; mi++) {
        __syncthreads();
#pragma unroll
        for (int ni = 0; ni < 4; ni++) {
            int col = wn * 64 + ni * 16 + fr;
#pragma unroll
            for (int reg = 0; reg < 4; reg++)
                Lt[(wm * 16 + quad * 4 + reg) * 260 + col] = acc[mi][ni][reg];
        }
        __syncthreads();
#pragma unroll
        for (int hf = 0; hf < 2; hf++) {
            int r = (tid >> 5) + hf * 16;
            int m = bm0 + (r >> 4) * 128 + mi * 16 + (r & 15);
            float vv[8];
            *(f32x4*)&vv[0] = *(const f32x4*)&Lt[r * 260 + colg];
            *(f32x4*)&vv[4] = *(const f32x4*)&Lt[r * 260 + colg + 4];
            bf16x4 xcv = *(const bf16x4*)(A + (size_t)m * DDIM + d0);
            bf16x4 og, ob;
#pragma unroll
            for (int j = 0; j < 4; j++) {
                float rv = 1.f / (1.f + __expf(-(vv[2 * j] + rb[j])));
                float iv = 1.f / (1.f + __expf(-(vv[2 * j + 1] + ibv[j])));
                float lga = 8.f * rv * lnab[j];
                float a = __expf(lga);
                float bt = sqrtf(fmaxf(1.f - a * a, 1e-6f)) * (iv * (float)xcv[j]);
                og[j] = (__bf16)lga;
                ob[j] = (__bf16)bt;
            }
            *(bf16x4*)(LOGA + (size_t)m * DDIM + d0) = og;
            *(bf16x4*)(BB + (size_t)m * DDIM + d0) = ob;
        }
    }
}

// HW = A @ Wo^T, same deep-pipelined structure + hoisted addressing.
__global__ __launch_bounds__(512, 2) void out_gemm(
    const __bf16* __restrict__ A, const __bf16* __restrict__ Wo, __bf16* __restrict__ HW) {
    __shared__ __attribute__((aligned(16))) __bf16 sm[65536]; // 128 KiB
    int tid = threadIdx.x;
    int wave = tid >> 6, lane = tid & 63;
    int wm = wave >> 2, wn = wave & 3;
    int fr = lane & 15, quad = lane >> 4;

    int nx = gridDim.x;
    int bid = blockIdx.y * nx + blockIdx.x;
    int cpx = (nx * gridDim.y) >> 3;
    int sw = (bid & 7) * cpx + (bid >> 3);
    int bm0 = (sw / nx) * 256;
    int bn0 = (sw % nx) * 256;

    const __bf16* Ag = A + (size_t)bm0 * DDIM;
    const __bf16* Bg = Wo + (size_t)bn0 * DDIM;

    f32x4 acc[8][4];
    f32x4 zero = {0.f, 0.f, 0.f, 0.f};
#pragma unroll
    for (int i = 0; i < 8; i++)
#pragma unroll
        for (int j = 0; j < 4; j++) acc[i][j] = zero;

    int offA[2][4], offB[4];
#pragma unroll
    for (int mh = 0; mh < 2; mh++)
#pragma unroll
        for (int mi = 0; mi < 4; mi++) {
            int row = wm * 128 + (mh * 4 + mi) * 16 + fr;
            offA[mh][mi] = row * 32 + ((quad ^ ((row >> 1) & 3)) << 3);
        }
#pragma unroll
    for (int ni = 0; ni < 4; ni++) {
        int row = wn * 64 + ni * 16 + fr;
        offB[ni] = 8192 + row * 32 + ((quad ^ ((row >> 1) & 3)) << 3);
    }
    int r0 = tid >> 2, g0 = (tid & 3) ^ ((r0 >> 1) & 3);
    int r1 = (512 + tid) >> 2, g1 = ((512 + tid) & 3) ^ ((r1 >> 1) & 3);
    const __bf16* gA0 = Ag + (size_t)r0 * DDIM + g0 * 8;
    const __bf16* gA1 = Ag + (size_t)r1 * DDIM + g1 * 8;
    const __bf16* gB0 = Bg + (size_t)r0 * DDIM + g0 * 8;
    const __bf16* gB1 = Bg + (size_t)r1 * DDIM + g1 * 8;
    int lb0 = wave * 512, lb1 = 4096 + wave * 512;

    auto STAGE = [&](int buf, const __bf16* pA0, const __bf16* pA1,
                     const __bf16* pB0, const __bf16* pB1, int tc) {
        int lo = buf * 16384;
        load16(pA0 + tc * BK32, sm + lo + lb0);
        load16(pA1 + tc * BK32, sm + lo + lb1);
        load16(pB0 + tc * BK32, sm + lo + 8192 + lb0);
        load16(pB1 + tc * BK32, sm + lo + 8192 + lb1);
    };

    STAGE(0, gA0, gA1, gB0, gB1, 0);
    STAGE(1, gA0, gA1, gB0, gB1, 1);
    STAGE(2, gA0, gA1, gB0, gB1, 2);
    for (int t4 = 0; t4 < NT32; t4 += 4) {
        const __bf16* pA0 = gA0 + (t4 + 3) * BK32;
        const __bf16* pA1 = gA1 + (t4 + 3) * BK32;
        const __bf16* pB0 = gB0 + (t4 + 3) * BK32;
        const __bf16* pB1 = gB1 + (t4 + 3) * BK32;
#pragma unroll
        for (int tt = 0; tt < 4; tt++) {
            int t = t4 + tt;
            if (t + 2 < NT32) { WAITV(8); }
            else if (t + 1 < NT32) { WAITV(4); }
            else { WAITV(0); }
            SBAR();
            if (t + 3 < NT32) STAGE((tt + 3) & 3, pA0, pA1, pB0, pB1, tt);
            const __bf16* base = sm + tt * 16384;
            bf16x8 bfm[4];
#pragma unroll
            for (int ni = 0; ni < 4; ni++) bfm[ni] = *(const bf16x8*)(base + offB[ni]);
#pragma unroll
            for (int mh = 0; mh < 2; mh++) {
                bf16x8 af[4];
#pragma unroll
                for (int mi = 0; mi < 4; mi++)
                    af[mi] = *(const bf16x8*)(base + offA[mh][mi]);
                __builtin_amdgcn_s_setprio(1);
#pragma unroll
                for (int ni = 0; ni < 4; ni++)
#pragma unroll
                    for (int mi = 0; mi < 4; mi++)
                        acc[mh * 4 + mi][ni] = __builtin_amdgcn_mfma_f32_16x16x32_bf16(
                            af[mi], bfm[ni], acc[mh * 4 + mi][ni], 0, 0, 0);
                __builtin_amdgcn_s_setprio(0);
            }
        }
    }

    float* Lt = (float*)&sm[0]; // [32][260]
    int colg = (tid & 31) * 8;
    int n0 = bn0 + colg;
#pragma unroll
    for (int mi = 0; mi < 8; mi++) {
        __syncthreads();
#pragma unroll
        for (int ni = 0; ni < 4; ni++) {
            int col = wn * 64 + ni * 16 + fr;
#pragma unroll
            for (int reg = 0; reg < 4; reg++)
                Lt[(wm * 16 + quad * 4 + reg) * 260 + col] = acc[mi][ni][reg];
        }
        __syncthreads();
#pragma unroll
        for (int hf = 0; hf < 2; hf++) {
            int r = (tid >> 5) + hf * 16;
            int m = bm0 + (r >> 4) * 128 + mi * 16 + (r & 15);
            float vv[8];
            *(f32x4*)&vv[0] = *(const f32x4*)&Lt[r * 260 + colg];
            *(f32x4*)&vv[4] = *(const f32x4*)&Lt[r * 260 + colg + 4];
            bf16x8 o;
#pragma unroll
            for (int j = 0; j < 8; j++) o[j] = (__bf16)vv[j];
            *(bf16x8*)(HW + (size_t)m * DDIM + n0) = o;
        }
    }
}

// Clamped log-space scan: 32 chunks x 64 steps, 1024-thread blocks (16 waves/CU).
#define SCH 32
#define SCT 64
__global__ __launch_bounds__(1024) void scan_kernel(const __bf16* __restrict__ LOGA,
                                                    const __bf16* __restrict__ BB,
                                                    __bf16* __restrict__ H) {
    int b = blockIdx.y;
    int dl = threadIdx.x & 31;
    int d = blockIdx.x * 32 + dl;
    int c = threadIdx.x >> 5;
    size_t base = ((size_t)b * LDIM + (size_t)c * SCT) * DDIM + d;
    const __bf16* pga = LOGA + base;
    const __bf16* pbb = BB + base;
    __bf16* pH = H + base;

    // pass 1: per-chunk log-sum
    float S = 0.f;
#pragma unroll 8
    for (int t = 0; t < SCT; t++) S += (float)pga[(size_t)t * DDIM];
    __shared__ float sS[SCH][32];
    sS[c][dl] = S;
    __syncthreads();
    float L0 = 0.f;
    for (int cc = 0; cc < c; cc++) L0 += sS[cc][dl];

    // pass 2: per-chunk (Ac, hB) with global clamp
    float Lr = L0, lcp = fmaxf(L0, -80.f), hB = 0.f;
#pragma unroll 4
    for (int t = 0; t < SCT; t++) {
        float lga = (float)pga[(size_t)t * DDIM];
        Lr += lga;
        float lc = fmaxf(Lr, -80.f);
        hB = __expf(lc - lcp) * hB + (float)pbb[(size_t)t * DDIM];
        lcp = lc;
    }
    float Ac = __expf(fmaxf(Lr, -80.f) - fmaxf(L0, -80.f));
    __shared__ float sA[SCH][32], sB[SCH][32];
    sA[c][dl] = Ac;
    sB[c][dl] = hB;
    __syncthreads();
    float hin = 0.f;
    for (int cc = 0; cc < c; cc++) hin = sA[cc][dl] * hin + sB[cc][dl];

    // pass 3: apply
    Lr = L0;
    lcp = fmaxf(L0, -80.f);
    float h = hin;
#pragma unroll 4
    for (int t = 0; t < SCT; t++) {
        float lga = (float)pga[(size_t)t * DDIM];
        Lr += lga;
        float lc = fmaxf(Lr, -80.f);
        h = __expf(lc - lcp) * h + (float)pbb[(size_t)t * DDIM];
        lcp = lc;
        pH[(size_t)t * DDIM] = (__bf16)h;
    }
}

// rmsnorm over last dim (1024); one block per row, 256 threads x 4 elems.
template <typename TI, typename TO>
__global__ __launch_bounds__(256) void rmsnorm_kernel(const TI* __restrict__ X,
                                                      const float* __restrict__ w,
                                                      TO* __restrict__ Y) {
    int row = blockIdx.x;
    int tid = threadIdx.x;
    size_t off = (size_t)row * DDIM + tid * 4;
    float v[4];
    if constexpr (std::is_same<TI, float>::value) {
        float4 t = *(const float4*)(X + off);
        v[0] = t.x; v[1] = t.y; v[2] = t.z; v[3] = t.w;
    } else {
        bf16x4 t = *(const bf16x4*)(X + off);
        v[0] = (float)t.x; v[1] = (float)t.y; v[2] = (float)t.z; v[3] = (float)t.w;
    }
    float s = v[0] * v[0] + v[1] * v[1] + v[2] * v[2] + v[3] * v[3];
#pragma unroll
    for (int o = 32; o > 0; o >>= 1) s += __shfl_down(s, o);
    __shared__ float sw[4];
    if ((tid & 63) == 0) sw[tid >> 6] = s;
    __syncthreads();
    float tot = sw[0] + sw[1] + sw[2] + sw[3];
    float scale = rsqrtf(tot * (1.f / (float)DDIM) + 1e-6f);
    float4 wv = ((const float4*)w)[tid];
    float o0 = v[0] * wv.x * scale, o1 = v[1] * wv.y * scale;
    float o2 = v[2] * wv.z * scale, o3 = v[3] * wv.w * scale;
    if constexpr (std::is_same<TO, float>::value) {
        float4 o = {o0, o1, o2, o3};
        *(float4*)(Y + off) = o;
    } else {
        bf16x4 o;
        o.x = (__bf16)o0; o.y = (__bf16)o1; o.z = (__bf16)o2; o.w = (__bf16)o3;
        *(bf16x4*)(Y + off) = o;
    }
}

extern "C" void kernel_launch(void* const* d_in, const int* in_sizes, int n_in,
                              void* d_out, int out_size, void* d_ws, size_t ws_size,
                              hipStream_t stream) {
    const float* x = (const float*)d_in[0];
    const float* conv_w = (const float*)d_in[1];
    const float* conv_b = (const float*)d_in[2];
    const float* wr_w = (const float*)d_in[3];
    const float* wr_b = (const float*)d_in[4];
    const float* wi_w = (const float*)d_in[5];
    const float* wi_b = (const float*)d_in[6];
    const float* log_a = (const float*)d_in[7];
    const float* wo_w = (const float*)d_in[8];
    const float* norm_w = (const float*)d_in[9];
    const float* norm_out_w = (const float*)d_in[10];

    const size_t W2SZ = (size_t)NL * 2 * DDIM * DDIM; /* interleaved r/i weight */
    const size_t WOSZ = (size_t)NL * DDIM * DDIM;
    const size_t MD = (size_t)MDIM * DDIM;
    __bf16* w2 = (__bf16*)d_ws;
    __bf16* wo16 = w2 + W2SZ;
    __bf16* XC = wo16 + WOSZ;
    __bf16* LGA = XC + MD;
    __bf16* BBf = LGA + MD;
    __bf16* Hb = BBf + MD;
    __bf16* HWb = Hb + MD;
    __bf16* PNb = HWb + MD;

    int nw = (int)WOSZ;
    cvt_interleave<<<(nw + 255) / 256, 256, 0, stream>>>(wr_w, wi_w, w2, nw);
    cvt_bf16<<<(nw + 255) / 256, 256, 0, stream>>>(wo_w, wo16, nw);

    for (int l = 0; l < NL; l++) {
        if (l == 0)
            conv_kernel<float><<<(MDIM * (DDIM / 4)) / 256, 256, 0, stream>>>(
                x, conv_w, conv_b, XC);
        else
            conv_kernel<__bf16><<<(MDIM * (DDIM / 4)) / 256, 256, 0, stream>>>(
                PNb, conv_w + (size_t)l * DDIM * K4, conv_b + (size_t)l * DDIM, XC);
        gate_gemm<<<dim3(2 * DDIM / 256, MDIM / 256), 512, 0, stream>>>(
            XC, w2 + (size_t)l * 2 * DDIM * DDIM,
            wr_b + (size_t)l * DDIM, wi_b + (size_t)l * DDIM, log_a + (size_t)l * DDIM,
            LGA, BBf);
        scan_kernel<<<dim3(DDIM / 32, BDIM), 1024, 0, stream>>>(LGA, BBf, Hb);
        out_gemm<<<dim3(DDIM / 256, MDIM / 256), 512, 0, stream>>>(
            Hb, wo16 + (size_t)l * DDIM * DDIM, HWb);
        rmsnorm_kernel<__bf16, __bf16><<<MDIM, 256, 0, stream>>>(
            HWb, norm_w + (size_t)l * DDIM, PNb);
    }
    rmsnorm_kernel<__bf16, float><<<MDIM, 256, 0, stream>>>(PNb, norm_out_w, (float*)d_out);
}